// Round 2
// baseline (251.623 us; speedup 1.0000x reference)
//
#include <hip/hip_runtime.h>

#define H 512
#define W 512
#define K 5
#define PAD 2
#define RPT 8   // output rows per thread
#define XPT 4   // output cols per thread (one float4)

// block (64,4): each thread computes a 4-wide x 8-tall output micro-tile.
// Per input row, 3 aligned float4 loads (left/mid/right) provide the 8-float
// window needed for 4 outputs; each input row feeds up to 5 output rows in
// registers. 1.1 loads/output @16B vs 7.5 @4B in the scalar version.
__global__ __launch_bounds__(256) void conv5x5_kernel(
    const float* __restrict__ X, const float* __restrict__ ker,
    float* __restrict__ out)
{
    const int tx  = threadIdx.x;                      // 0..63
    const int xb  = (blockIdx.x * 64 + tx) * XPT;     // 0,4,...,508
    const int y0  = (blockIdx.y * 4 + threadIdx.y) * RPT;
    const int img = blockIdx.z;                       // 0..127

    const float* Xp = X   + (size_t)img * H * W;
    float*       Op = out + (size_t)img * H * W;

    float kk[K][K];
    #pragma unroll
    for (int i = 0; i < K; ++i)
        #pragma unroll
        for (int j = 0; j < K; ++j)
            kk[i][j] = ker[i * K + j];

    float acc[RPT][XPT];
    #pragma unroll
    for (int o = 0; o < RPT; ++o)
        #pragma unroll
        for (int j = 0; j < XPT; ++j)
            acc[o][j] = 0.f;

    const bool okL = (xb - 4) >= 0;       // false only for lane 0 of x-block 0
    const bool okR = (xb + 7) < W;        // false only for last lane of last x-block
    const int  q   = xb >> 2;             // float4 column index

    #pragma unroll
    for (int r = 0; r < RPT + K - 1; ++r) {   // 12 input rows
        const int yr = y0 - PAD + r;
        float4 Lv = {0.f, 0.f, 0.f, 0.f};
        float4 Mv = {0.f, 0.f, 0.f, 0.f};
        float4 Rv = {0.f, 0.f, 0.f, 0.f};
        if (yr >= 0 && yr < H) {              // wave-uniform branch (y0 per-wave)
            const float4* rp = (const float4*)(Xp + (size_t)yr * W);
            Mv = rp[q];
            if (okL) Lv = rp[q - 1];
            if (okR) Rv = rp[q + 1];
        }
        // window v[0..7] = input columns xb-2 .. xb+5
        float v[8] = {Lv.z, Lv.w, Mv.x, Mv.y, Mv.z, Mv.w, Rv.x, Rv.y};

        #pragma unroll
        for (int o = 0; o < RPT; ++o) {
            const int kr = r - o;
            if (kr >= 0 && kr < K) {
                #pragma unroll
                for (int c = 0; c < K; ++c)
                    #pragma unroll
                    for (int j = 0; j < XPT; ++j)
                        acc[o][j] = fmaf(v[j + c], kk[kr][c], acc[o][j]);
            }
        }
    }

    #pragma unroll
    for (int o = 0; o < RPT; ++o) {
        float4 st = {acc[o][0], acc[o][1], acc[o][2], acc[o][3]};
        *(float4*)(Op + (size_t)(y0 + o) * W + xb) = st;
    }
}

extern "C" void kernel_launch(void* const* d_in, const int* in_sizes, int n_in,
                              void* d_out, int out_size, void* d_ws, size_t ws_size,
                              hipStream_t stream) {
    const float* X   = (const float*)d_in[0];
    const float* ker = (const float*)d_in[1];
    float* out = (float*)d_out;

    dim3 block(64, 4, 1);
    dim3 grid(W / (64 * XPT), H / (4 * RPT), 4 * 32);  // (2, 16, 128)
    hipLaunchKernelGGL(conv5x5_kernel, grid, block, 0, stream, X, ker, out);
}

// Round 4
// 231.842 us; speedup vs baseline: 1.0853x; 1.0853x over previous
//
#include <hip/hip_runtime.h>

#define H 512
#define W 512
#define K 5
#define PAD 2
#define RPT 4   // output rows per thread
#define XPT 4   // output cols per thread (one float4)

typedef float vf4 __attribute__((ext_vector_type(4)));  // native vector: OK for nontemporal builtins

// block (64,4): each thread computes a 4-wide x 4-tall output tile.
// VGPR < 64 (32-waves/CU cap), clamped edge addresses (unconditional loads),
// edge values zeroed by 0/1 multiplies, float4 loads, nontemporal stores.
__global__ __launch_bounds__(256) void conv5x5_kernel(
    const float* __restrict__ X, const float* __restrict__ ker,
    float* __restrict__ out)
{
    const int tx  = threadIdx.x;                      // 0..63
    const int xb  = (blockIdx.x * 64 + tx) * XPT;     // 0,4,...,508
    const int y0  = blockIdx.y * (4 * RPT) + threadIdx.y * RPT;
    const int img = blockIdx.z;                       // 0..127

    const float* Xp = X   + (size_t)img * H * W;
    float*       Op = out + (size_t)img * H * W;

    float kk[K][K];
    #pragma unroll
    for (int i = 0; i < K; ++i)
        #pragma unroll
        for (int j = 0; j < K; ++j)
            kk[i][j] = ker[i * K + j];

    float acc[RPT][XPT];
    #pragma unroll
    for (int o = 0; o < RPT; ++o)
        #pragma unroll
        for (int j = 0; j < XPT; ++j)
            acc[o][j] = 0.f;

    const int q  = xb >> 2;                           // float4 col index 0..127
    const int qL = (q == 0) ? 0 : q - 1;              // clamped: always in-bounds
    const int qR = (q == W / 4 - 1) ? q : q + 1;
    const float mLo = (q == 0) ? 0.f : 1.f;           // zero v[0],v[1] at left edge
    const float mHi = (q == W / 4 - 1) ? 0.f : 1.f;   // zero v[6],v[7] at right edge

    #pragma unroll
    for (int r = 0; r < RPT + K - 1; ++r) {           // 8 input rows
        const int yr = y0 - PAD + r;
        vf4 Lv = {0.f, 0.f, 0.f, 0.f};
        vf4 Mv = {0.f, 0.f, 0.f, 0.f};
        vf4 Rv = {0.f, 0.f, 0.f, 0.f};
        if (yr >= 0 && yr < H) {                      // wave-uniform branch
            const vf4* rp = (const vf4*)(Xp + (size_t)yr * W);
            Lv = rp[qL];
            Mv = rp[q];
            Rv = rp[qR];
        }
        // window v[0..7] = input cols xb-2 .. xb+5; edge lanes zeroed by mask
        float v[8];
        v[0] = Lv.z * mLo;  v[1] = Lv.w * mLo;
        v[2] = Mv.x;  v[3] = Mv.y;  v[4] = Mv.z;  v[5] = Mv.w;
        v[6] = Rv.x * mHi;  v[7] = Rv.y * mHi;

        #pragma unroll
        for (int o = 0; o < RPT; ++o) {
            const int kr = r - o;
            if (kr >= 0 && kr < K) {
                #pragma unroll
                for (int c = 0; c < K; ++c)
                    #pragma unroll
                    for (int j = 0; j < XPT; ++j)
                        acc[o][j] = fmaf(v[j + c], kk[kr][c], acc[o][j]);
            }
        }
    }

    #pragma unroll
    for (int o = 0; o < RPT; ++o) {
        vf4 st = {acc[o][0], acc[o][1], acc[o][2], acc[o][3]};
        __builtin_nontemporal_store(st, (vf4*)(Op + (size_t)(y0 + o) * W + xb));
    }
}

extern "C" void kernel_launch(void* const* d_in, const int* in_sizes, int n_in,
                              void* d_out, int out_size, void* d_ws, size_t ws_size,
                              hipStream_t stream) {
    const float* X   = (const float*)d_in[0];
    const float* ker = (const float*)d_in[1];
    float* out = (float*)d_out;

    dim3 block(64, 4, 1);
    dim3 grid(W / (64 * XPT), H / (4 * RPT), 4 * 32);  // (2, 32, 128)
    hipLaunchKernelGGL(conv5x5_kernel, grid, block, 0, stream, X, ker, out);
}